// Round 11
// baseline (148.894 us; speedup 1.0000x reference)
//
#include <hip/hip_runtime.h>

// Problem constants (fixed by setup_inputs)
#define BS 4
#define NH 8
#define TT 1024         // T = 32*32
#define WROWS 1536      // 3*NH*CH
#define NOBJ 8
#define NT 65536        // per-bh tensor elems (64*1024)

// Workspace layout (short element offsets)
#define QNT_OFF  0
#define KNT_OFF  2097152
#define VNCS_OFF 4194304
#define QFT_OFF  6291456
#define KFT_OFF  8388608
#define VFT_OFF  10485760

typedef __attribute__((ext_vector_type(8))) short short8;
typedef __attribute__((ext_vector_type(4))) float v4f;

__device__ __forceinline__ short f2bf(float f) {
    unsigned u = __float_as_uint(f);
    u = (u + 0x7FFF + ((u >> 16) & 1)) >> 16;   // RNE
    return (short)u;
}
// packed f32x2 -> bf16x2 (RNE), lo = a, hi = b
__device__ __forceinline__ unsigned cvtpk(float a, float b) {
    unsigned u;
    asm("v_cvt_pk_bf16_f32 %0, %1, %2" : "=v"(u) : "v"(a), "v"(b));
    return u;
}
// 2^x via the HW transcendental (avoids glibc __exp2f name clash)
__device__ __forceinline__ float fexp2(float x) {
    float r;
    asm("v_exp_f32 %0, %1" : "=v"(r) : "v"(x));
    return r;
}
// pi-permutation of s-position within a 64-tile: s -> 4*(s&15) + (s>>4).
__device__ __forceinline__ int pi64(int s) { return 4 * (s & 15) + (s >> 4); }

__device__ __forceinline__ void get_region(const float* __restrict__ bb,
                                           int& i0, int& j0, int& hh, int& ww) {
    float x = bb[0], y = bb[1], bw = bb[2], bh = bb[3];
    float i0f = fminf(31.0f, floorf(y * 32.0f));
    float j0f = fminf(31.0f, floorf(x * 32.0f));
    float i1f = i0f + fmaxf(1.0f, ceilf(bh * 32.0f));
    float j1f = j0f + fmaxf(1.0f, ceilf(bw * 32.0f));
    i0 = (int)i0f; j0 = (int)j0f;
    int i1 = min(32, (int)i1f);
    int j1 = min(32, (int)j1f);
    hh = i1 - i0; ww = j1 - j0;
}

// ---------------------------------------------------------------------------
// Kernel 1: fused projection + layout conversion on MFMA (verified R7 version,
// unchanged). E staged transposed bf16 [t][e] in LDS; W A-frags bf16 direct.
// Outputs: q/k/fgV transposed [t][c]; null V pre-permuted [c][pi(p)].
// Q scaled by 0.125*log2(e) so attention uses exp2.
// ---------------------------------------------------------------------------
__global__ __launch_bounds__(256)
void fuse_kernel(const float* __restrict__ qkv, const float* __restrict__ nEmb,
                 const float* __restrict__ pEmb, const float* __restrict__ W,
                 short* __restrict__ wsS) {
    __shared__ __align__(16) short Ent[64 * 72];
    __shared__ __align__(16) short Ept[64 * 72];
    __shared__ __align__(16) short sbuf[64 * 72];
    int t0 = blockIdx.x * 64;
    int r0 = blockIdx.y * 64;
    int b  = blockIdx.z;
    int tid = threadIdx.x;
    int w = tid >> 6, lane = tid & 63, ln = lane & 15, qd = lane >> 4;

    // stage E (null & prompt) transposed to bf16 [t][e], pitch 72
    {
        int e  = tid >> 4;
        int t4 = (tid & 15) * 4;
#pragma unroll
        for (int p = 0; p < 4; ++p) {
            int ee = p * 16 + e;
            float4 n4 = *(const float4*)&nEmb[(b * 64 + ee) * TT + t0 + t4];
            float4 p4 = *(const float4*)&pEmb[(b * 64 + ee) * TT + t0 + t4];
            Ent[(t4 + 0) * 72 + ee] = f2bf(n4.x); Ent[(t4 + 1) * 72 + ee] = f2bf(n4.y);
            Ent[(t4 + 2) * 72 + ee] = f2bf(n4.z); Ent[(t4 + 3) * 72 + ee] = f2bf(n4.w);
            Ept[(t4 + 0) * 72 + ee] = f2bf(p4.x); Ept[(t4 + 1) * 72 + ee] = f2bf(p4.y);
            Ept[(t4 + 2) * 72 + ee] = f2bf(p4.z); Ept[(t4 + 3) * 72 + ee] = f2bf(p4.w);
        }
    }
    // W A-fragments (bf16) direct from global: lane ln -> row r0+16w+ln
    short8 aw0, aw1;
    {
        const float* wp = &W[(r0 + 16 * w + ln) * 64 + qd * 8];
        float4 f0 = *(const float4*)wp;
        float4 f1 = *(const float4*)(wp + 4);
        float4 f2 = *(const float4*)(wp + 32);
        float4 f3 = *(const float4*)(wp + 36);
        uint4 u0, u1;
        u0.x = cvtpk(f0.x, f0.y); u0.y = cvtpk(f0.z, f0.w);
        u0.z = cvtpk(f1.x, f1.y); u0.w = cvtpk(f1.z, f1.w);
        u1.x = cvtpk(f2.x, f2.y); u1.y = cvtpk(f2.z, f2.w);
        u1.z = cvtpk(f3.x, f3.y); u1.w = cvtpk(f3.z, f3.w);
        aw0 = *(short8*)&u0; aw1 = *(short8*)&u1;
    }
    __syncthreads();
    // MFMA: D[row=16w+4qd+i][col=nn*16+ln] = sum_e W[row][e]*E[e][col]
    v4f accN[4], accP[4];
#pragma unroll
    for (int nn = 0; nn < 4; ++nn) {
        const short* bp = &Ent[(nn * 16 + ln) * 72 + qd * 8];
        short8 b0 = *(const short8*)bp;
        short8 b1 = *(const short8*)(bp + 32);
        v4f z = (v4f){0.f, 0.f, 0.f, 0.f};
        z = __builtin_amdgcn_mfma_f32_16x16x32_bf16(aw0, b0, z, 0, 0, 0);
        z = __builtin_amdgcn_mfma_f32_16x16x32_bf16(aw1, b1, z, 0, 0, 0);
        accN[nn] = z;
        const short* cp = &Ept[(nn * 16 + ln) * 72 + qd * 8];
        short8 c0 = *(const short8*)cp;
        short8 c1 = *(const short8*)(cp + 32);
        v4f y = (v4f){0.f, 0.f, 0.f, 0.f};
        y = __builtin_amdgcn_mfma_f32_16x16x32_bf16(aw0, c0, y, 0, 0, 0);
        y = __builtin_amdgcn_mfma_f32_16x16x32_bf16(aw1, c1, y, 0, 0, 0);
        accP[nn] = y;
    }
    // add qkv + scale
    int sec = (r0 % 192) / 64;          // 0=q 1=k 2=v
    int h = r0 / 192, bh = b * 8 + h;
    float sc = (sec == 0) ? 0.18033688f : 1.0f;   // 0.125*log2e folded into Q
    float xan[4][4], xap[4][4];                    // [nn][i]
#pragma unroll
    for (int nn = 0; nn < 4; ++nn)
#pragma unroll
        for (int i = 0; i < 4; ++i) {
            int r = r0 + 16 * w + 4 * qd + i;
            float x = qkv[(b * WROWS + r) * TT + t0 + nn * 16 + ln];
            xan[nn][i] = (accN[nn][i] + x) * sc;
            xap[nn][i] = (accP[nn][i] + x) * sc;
        }

    if (sec == 2) {
        // pass 1: null V pre-permuted [c][pi(p)]: row c = 16w+4qd+i, col 4ln+nn
        short* Vn = wsS + VNCS_OFF + bh * NT;
        __syncthreads();
#pragma unroll
        for (int nn = 0; nn < 4; ++nn)
#pragma unroll
            for (int i = 0; i < 4; ++i)
                sbuf[(16 * w + 4 * qd + i) * 72 + 4 * ln + nn] = f2bf(xan[nn][i]);
        __syncthreads();
#pragma unroll
        for (int rep = 0; rep < 2; ++rep) {
            int idx = rep * 256 + tid; int cl = idx >> 3, c8 = idx & 7;
            *(short8*)&Vn[cl * TT + t0 + c8 * 8] = *(const short8*)&sbuf[cl * 72 + c8 * 8];
        }
        __syncthreads();
        // pass 2: fg V transposed [t][c]: row t = nn*16+ln, cols 16w+4qd..+3
        short* dst = wsS + VFT_OFF + bh * NT + t0 * 64;
#pragma unroll
        for (int nn = 0; nn < 4; ++nn) {
            uint2 u; u.x = cvtpk(xap[nn][0], xap[nn][1]); u.y = cvtpk(xap[nn][2], xap[nn][3]);
            *(uint2*)&sbuf[(nn * 16 + ln) * 72 + 16 * w + 4 * qd] = u;
        }
        __syncthreads();
#pragma unroll
        for (int rep = 0; rep < 2; ++rep) {
            int idx = rep * 256 + tid; int tl = idx >> 3, c8 = idx & 7;
            *(short8*)&dst[tl * 64 + c8 * 8] = *(const short8*)&sbuf[tl * 72 + c8 * 8];
        }
    } else {
        short* dn = wsS + (sec == 0 ? QNT_OFF : KNT_OFF) + bh * NT + t0 * 64;
        short* df = wsS + (sec == 0 ? QFT_OFF : KFT_OFF) + bh * NT + t0 * 64;
        __syncthreads();
        // pass 1: null, transposed [t][c]
#pragma unroll
        for (int nn = 0; nn < 4; ++nn) {
            uint2 u; u.x = cvtpk(xan[nn][0], xan[nn][1]); u.y = cvtpk(xan[nn][2], xan[nn][3]);
            *(uint2*)&sbuf[(nn * 16 + ln) * 72 + 16 * w + 4 * qd] = u;
        }
        __syncthreads();
#pragma unroll
        for (int rep = 0; rep < 2; ++rep) {
            int idx = rep * 256 + tid; int tl = idx >> 3, c8 = idx & 7;
            *(short8*)&dn[tl * 64 + c8 * 8] = *(const short8*)&sbuf[tl * 72 + c8 * 8];
        }
        __syncthreads();
        // pass 2: fg, transposed [t][c]
#pragma unroll
        for (int nn = 0; nn < 4; ++nn) {
            uint2 u; u.x = cvtpk(xap[nn][0], xap[nn][1]); u.y = cvtpk(xap[nn][2], xap[nn][3]);
            *(uint2*)&sbuf[(nn * 16 + ln) * 72 + 16 * w + 4 * qd] = u;
        }
        __syncthreads();
#pragma unroll
        for (int rep = 0; rep < 2; ++rep) {
            int idx = rep * 256 + tid; int tl = idx >> 3, c8 = idx & 7;
            *(short8*)&df[tl * 64 + c8 * 8] = *(const short8*)&sbuf[tl * 72 + c8 * 8];
        }
    }
}

// ---------------------------------------------------------------------------
// Kernel 2: fused null + foreground attention. Change vs R10 (single change):
// DOUBLE-BUFFERED K/V staging -> ONE barrier per tile (was 2). Iter ct writes
// next tile into buf[cur^1] (last read in iter ct-1, fenced by its barrier)
// while computing from buf[cur]; end-of-iter barrier publishes the writes.
// Null: 32 -> 17 barriers. FG: 2/tile -> 1/tile + 2/object.
// bh-major grid kept (FETCH 58.7 -> 11.2 MB, verified R10).
// ---------------------------------------------------------------------------
__global__ __launch_bounds__(256)
void attn_fused(const short* __restrict__ wsS, const float* __restrict__ bboxes,
                float* __restrict__ out) {
    __shared__ __align__(16) short lds[23040];   // Qs + K[2] + V[2], 46 KB
    __shared__ unsigned short tmap[1024];
    short* Qs  = lds;             // [64][72] Q stage / wave-private P rows
    short* Kb0 = lds + 4608;      // K buffers [64][72] x2
    short* Kb1 = lds + 9216;
    short* Vb0 = lds + 13824;     // V buffers [64][72] x2 ([c][pi(s)])
    short* Vb1 = lds + 18432;
    int bh = blockIdx.x, rt = blockIdx.y;   // bh-major: XCD = bh % 8
    int b = bh >> 3, h = bh & 7;
    int t0 = rt * 64;
    int tid = threadIdx.x;
    int w = tid >> 6, lane = tid & 63, ln = lane & 15, qd = lane >> 4;
    const short* QnT = wsS + QNT_OFF + bh * NT;
    const short* KnT = wsS + KNT_OFF + bh * NT;
    const short* Vn  = wsS + VNCS_OFF + bh * NT;   // pre-permuted [c][pi]
    const short* QfT = wsS + QFT_OFF + bh * NT;
    const short* KfT = wsS + KFT_OFF + bh * NT;
    const short* VfT = wsS + VFT_OFF + bh * NT;
    int sidx = tid, scell = sidx >> 3, sc8 = sidx & 7;      // staging coords lo
    int sidx2 = 256 + tid, scell2 = sidx2 >> 3, sc82 = sidx2 & 7;

    // ================= Phase 1: null attention =================
    *(short8*)&Qs[scell * 72 + sc8 * 8]  = *(const short8*)&QnT[(t0 + scell) * 64 + sc8 * 8];
    *(short8*)&Qs[scell2 * 72 + sc82 * 8] = *(const short8*)&QnT[(t0 + scell2) * 64 + sc82 * 8];
    __syncthreads();
    short8 aq0 = *(const short8*)&Qs[(16 * w + ln) * 72 + qd * 8];
    short8 aq1 = *(const short8*)&Qs[(16 * w + ln) * 72 + 32 + qd * 8];
    v4f O[4]; float l[4];
#pragma unroll
    for (int r = 0; r < 4; ++r) l[r] = 0.f;
#pragma unroll
    for (int cc = 0; cc < 4; ++cc) O[cc] = (v4f){0.f, 0.f, 0.f, 0.f};
    short8 kreg[2], vreg[2];
    // prologue: tile0 -> buf0; prefetch tile1 into regs
    kreg[0] = *(const short8*)&KnT[scell * 64 + sc8 * 8];
    kreg[1] = *(const short8*)&KnT[scell2 * 64 + sc82 * 8];
    vreg[0] = *(const short8*)&Vn[scell * TT + sc8 * 8];
    vreg[1] = *(const short8*)&Vn[scell2 * TT + sc82 * 8];
    *(short8*)&Kb0[scell * 72 + sc8 * 8]  = kreg[0];
    *(short8*)&Kb0[scell2 * 72 + sc82 * 8] = kreg[1];
    *(short8*)&Vb0[scell * 72 + sc8 * 8]  = vreg[0];
    *(short8*)&Vb0[scell2 * 72 + sc82 * 8] = vreg[1];
    kreg[0] = *(const short8*)&KnT[(64 + scell) * 64 + sc8 * 8];
    kreg[1] = *(const short8*)&KnT[(64 + scell2) * 64 + sc82 * 8];
    vreg[0] = *(const short8*)&Vn[scell * TT + 64 + sc8 * 8];
    vreg[1] = *(const short8*)&Vn[scell2 * TT + 64 + sc82 * 8];
    __syncthreads();   // buf0 ready
    for (int ct = 0; ct < 16; ++ct) {
        const short* Kc = (ct & 1) ? Kb1 : Kb0;
        const short* Vc = (ct & 1) ? Vb1 : Vb0;
        short* Kn_ = (ct & 1) ? Kb0 : Kb1;
        short* Vn_ = (ct & 1) ? Vb0 : Vb1;
        if (ct < 15) {
            *(short8*)&Kn_[scell * 72 + sc8 * 8]  = kreg[0];
            *(short8*)&Kn_[scell2 * 72 + sc82 * 8] = kreg[1];
            *(short8*)&Vn_[scell * 72 + sc8 * 8]  = vreg[0];
            *(short8*)&Vn_[scell2 * 72 + sc82 * 8] = vreg[1];
        }
        if (ct < 14) {
            int s0 = (ct + 2) * 64;
            kreg[0] = *(const short8*)&KnT[(s0 + scell) * 64 + sc8 * 8];
            kreg[1] = *(const short8*)&KnT[(s0 + scell2) * 64 + sc82 * 8];
            vreg[0] = *(const short8*)&Vn[scell * TT + s0 + sc8 * 8];
            vreg[1] = *(const short8*)&Vn[scell2 * TT + s0 + sc82 * 8];
        }
        v4f S[4];
#pragma unroll
        for (int nn = 0; nn < 4; ++nn) {
            short8 b0 = *(const short8*)&Kc[(nn * 16 + ln) * 72 + qd * 8];
            short8 b1 = *(const short8*)&Kc[(nn * 16 + ln) * 72 + 32 + qd * 8];
            v4f z = (v4f){0.f, 0.f, 0.f, 0.f};
            z = __builtin_amdgcn_mfma_f32_16x16x32_bf16(aq0, b0, z, 0, 0, 0);
            z = __builtin_amdgcn_mfma_f32_16x16x32_bf16(aq1, b1, z, 0, 0, 0);
            S[nn] = z;
        }
#pragma unroll
        for (int r = 0; r < 4; ++r) {
            float e0 = fexp2(S[0][r]);
            float e1 = fexp2(S[1][r]);
            float e2 = fexp2(S[2][r]);
            float e3 = fexp2(S[3][r]);
            l[r] += (e0 + e1) + (e2 + e3);
            uint2 u; u.x = cvtpk(e0, e1); u.y = cvtpk(e2, e3);
            *(uint2*)&Qs[(w * 16 + 4 * qd + r) * 72 + 4 * ln] = u;   // cols pi(s)
        }
        short8 ap0 = *(const short8*)&Qs[(w * 16 + ln) * 72 + qd * 8];
        short8 ap1 = *(const short8*)&Qs[(w * 16 + ln) * 72 + 32 + qd * 8];
#pragma unroll
        for (int cc = 0; cc < 4; ++cc) {
            short8 bv0 = *(const short8*)&Vc[(cc * 16 + ln) * 72 + qd * 8];
            short8 bv1 = *(const short8*)&Vc[(cc * 16 + ln) * 72 + 32 + qd * 8];
            O[cc] = __builtin_amdgcn_mfma_f32_16x16x32_bf16(ap0, bv0, O[cc], 0, 0, 0);
            O[cc] = __builtin_amdgcn_mfma_f32_16x16x32_bf16(ap1, bv1, O[cc], 0, 0, 0);
        }
        __syncthreads();   // publish next buf; all reads of cur done
    }
    v4f Onull[4];
#pragma unroll
    for (int r = 0; r < 4; ++r) {
        float rs = l[r];
        rs += __shfl_xor(rs, 1, 64);
        rs += __shfl_xor(rs, 2, 64);
        rs += __shfl_xor(rs, 4, 64);
        rs += __shfl_xor(rs, 8, 64);
        float inv = 1.0f / rs;
#pragma unroll
        for (int cc = 0; cc < 4; ++cc) Onull[cc][r] = O[cc][r] * inv;
    }

    // ================= Phase 2: foreground objects =================
    *(short8*)&Qs[scell * 72 + sc8 * 8]  = *(const short8*)&QfT[(t0 + scell) * 64 + sc8 * 8];
    *(short8*)&Qs[scell2 * 72 + sc82 * 8] = *(const short8*)&QfT[(t0 + scell2) * 64 + sc82 * 8];
    __syncthreads();
    aq0 = *(const short8*)&Qs[(16 * w + ln) * 72 + qd * 8];
    aq1 = *(const short8*)&Qs[(16 * w + ln) * 72 + 32 + qd * 8];
    v4f Oacc[4]; float cnt[4];
#pragma unroll
    for (int r = 0; r < 4; ++r) cnt[r] = 0.f;
#pragma unroll
    for (int cc = 0; cc < 4; ++cc) Oacc[cc] = (v4f){0.f, 0.f, 0.f, 0.f};
    int pA = pi64(scell), pB = pi64(scell2);

    for (int o = 0; o < NOBJ; ++o) {
        int i0, j0, hh, ww;
        get_region(&bboxes[(b * NOBJ + o) * 5], i0, j0, hh, ww);
        int i1 = i0 + hh;
        if (i0 > 2 * rt + 1 || i1 <= 2 * rt) continue;   // uniform per block
        int R = hh * ww;
        for (int idx = tid; idx < R; idx += 256) {
            int ri = idx / ww; int rj = idx - ri * ww;
            tmap[idx] = (unsigned short)((i0 + ri) * 32 + j0 + rj);
        }
        __syncthreads();   // tmap visible; prior buffer reads all fenced
#pragma unroll
        for (int r = 0; r < 4; ++r) l[r] = 0.f;
#pragma unroll
        for (int cc = 0; cc < 4; ++cc) O[cc] = (v4f){0.f, 0.f, 0.f, 0.f};
        int nct = (R + 63) >> 6;
        // prologue: tile0 -> buf0; prefetch tile1 into regs
        {
            int tA = tmap[min(scell, R - 1)];
            int tB = tmap[min(scell2, R - 1)];
            kreg[0] = *(const short8*)&KfT[tA * 64 + sc8 * 8];
            kreg[1] = *(const short8*)&KfT[tB * 64 + sc82 * 8];
            vreg[0] = *(const short8*)&VfT[tA * 64 + sc8 * 8];
            vreg[1] = *(const short8*)&VfT[tB * 64 + sc82 * 8];
        }
        *(short8*)&Kb0[scell * 72 + sc8 * 8]  = kreg[0];
        *(short8*)&Kb0[scell2 * 72 + sc82 * 8] = kreg[1];
#pragma unroll
        for (int jj = 0; jj < 8; ++jj) {
            int j = (jj + sc8) & 7;
            Vb0[(sc8 * 8 + j) * 72 + pA] = vreg[0][j];
        }
#pragma unroll
        for (int jj = 0; jj < 8; ++jj) {
            int j = (jj + sc82) & 7;
            Vb0[(sc82 * 8 + j) * 72 + pB] = vreg[1][j];
        }
        if (nct > 1) {
            int tA = tmap[min(64 + scell, R - 1)];
            int tB = tmap[min(64 + scell2, R - 1)];
            kreg[0] = *(const short8*)&KfT[tA * 64 + sc8 * 8];
            kreg[1] = *(const short8*)&KfT[tB * 64 + sc82 * 8];
            vreg[0] = *(const short8*)&VfT[tA * 64 + sc8 * 8];
            vreg[1] = *(const short8*)&VfT[tB * 64 + sc82 * 8];
        }
        __syncthreads();   // buf0 ready
        for (int ct = 0; ct < nct; ++ct) {
            int sb = ct * 64;
            const short* Kc = (ct & 1) ? Kb1 : Kb0;
            const short* Vc = (ct & 1) ? Vb1 : Vb0;
            short* Kn_ = (ct & 1) ? Kb0 : Kb1;
            short* Vn_ = (ct & 1) ? Vb0 : Vb1;
            if (ct + 1 < nct) {
                *(short8*)&Kn_[scell * 72 + sc8 * 8]  = kreg[0];
                *(short8*)&Kn_[scell2 * 72 + sc82 * 8] = kreg[1];
#pragma unroll
                for (int jj = 0; jj < 8; ++jj) {
                    int j = (jj + sc8) & 7;
                    Vn_[(sc8 * 8 + j) * 72 + pA] = vreg[0][j];
                }
#pragma unroll
                for (int jj = 0; jj < 8; ++jj) {
                    int j = (jj + sc82) & 7;
                    Vn_[(sc82 * 8 + j) * 72 + pB] = vreg[1][j];
                }
            }
            if (ct + 2 < nct) {
                int s0 = sb + 128;
                int tA = tmap[min(s0 + scell, R - 1)];
                int tB = tmap[min(s0 + scell2, R - 1)];
                kreg[0] = *(const short8*)&KfT[tA * 64 + sc8 * 8];
                kreg[1] = *(const short8*)&KfT[tB * 64 + sc82 * 8];
                vreg[0] = *(const short8*)&VfT[tA * 64 + sc8 * 8];
                vreg[1] = *(const short8*)&VfT[tB * 64 + sc82 * 8];
            }
            v4f S[4];
#pragma unroll
            for (int nn = 0; nn < 4; ++nn) {
                short8 b0 = *(const short8*)&Kc[(nn * 16 + ln) * 72 + qd * 8];
                short8 b1 = *(const short8*)&Kc[(nn * 16 + ln) * 72 + 32 + qd * 8];
                v4f z = (v4f){0.f, 0.f, 0.f, 0.f};
                z = __builtin_amdgcn_mfma_f32_16x16x32_bf16(aq0, b0, z, 0, 0, 0);
                z = __builtin_amdgcn_mfma_f32_16x16x32_bf16(aq1, b1, z, 0, 0, 0);
                S[nn] = z;
            }
            float v0 = (sb +  0 + ln) < R ? 1.f : 0.f;
            float v1 = (sb + 16 + ln) < R ? 1.f : 0.f;
            float v2 = (sb + 32 + ln) < R ? 1.f : 0.f;
            float v3 = (sb + 48 + ln) < R ? 1.f : 0.f;
#pragma unroll
            for (int r = 0; r < 4; ++r) {
                float e0 = fexp2(S[0][r]) * v0;
                float e1 = fexp2(S[1][r]) * v1;
                float e2 = fexp2(S[2][r]) * v2;
                float e3 = fexp2(S[3][r]) * v3;
                l[r] += (e0 + e1) + (e2 + e3);
                uint2 u; u.x = cvtpk(e0, e1); u.y = cvtpk(e2, e3);
                *(uint2*)&Qs[(w * 16 + 4 * qd + r) * 72 + 4 * ln] = u;
            }
            short8 ap0 = *(const short8*)&Qs[(w * 16 + ln) * 72 + qd * 8];
            short8 ap1 = *(const short8*)&Qs[(w * 16 + ln) * 72 + 32 + qd * 8];
#pragma unroll
            for (int cc = 0; cc < 4; ++cc) {
                short8 bv0 = *(const short8*)&Vc[(cc * 16 + ln) * 72 + qd * 8];
                short8 bv1 = *(const short8*)&Vc[(cc * 16 + ln) * 72 + 32 + qd * 8];
                O[cc] = __builtin_amdgcn_mfma_f32_16x16x32_bf16(ap0, bv0, O[cc], 0, 0, 0);
                O[cc] = __builtin_amdgcn_mfma_f32_16x16x32_bf16(ap1, bv1, O[cc], 0, 0, 0);
            }
            __syncthreads();   // publish next buf; all reads of cur done
        }
        // finalize object: accumulate rows inside region
#pragma unroll
        for (int r = 0; r < 4; ++r) {
            float rs = l[r];
            rs += __shfl_xor(rs, 1, 64);
            rs += __shfl_xor(rs, 2, 64);
            rs += __shfl_xor(rs, 4, 64);
            rs += __shfl_xor(rs, 8, 64);
            float inv = 1.0f / rs;
            int t = t0 + 16 * w + 4 * qd + r;
            int ti = t >> 5, tj = t & 31;
            bool in = (ti >= i0) && (ti < i1) && (tj >= j0) && (tj < j0 + ww);
            if (in) {
                cnt[r] += 1.f;
#pragma unroll
                for (int cc = 0; cc < 4; ++cc) Oacc[cc][r] += O[cc][r] * inv;
            }
        }
    }

    // ================= Epilogue =================
    __syncthreads();
    float* Ot = (float*)lds;   // [64][68] floats = 17408 B (fits in 46080 B)
#pragma unroll
    for (int r = 0; r < 4; ++r) {
        int tl = 16 * w + 4 * qd + r;
        float icnt = cnt[r] > 0.f ? 1.0f / cnt[r] : 0.f;
#pragma unroll
        for (int cc = 0; cc < 4; ++cc) {
            float val = cnt[r] > 0.f ? Oacc[cc][r] * icnt : Onull[cc][r];
            Ot[(cc * 16 + ln) * 68 + tl] = val;
        }
    }
    __syncthreads();
    int obase = (b * 512 + h * 64) * TT + t0;
#pragma unroll
    for (int rep = 0; rep < 4; ++rep) {
        int idx = rep * 256 + tid; int c = idx >> 4, t4 = (idx & 15) * 4;
        *(float4*)&out[obase + c * TT + t4] = *(float4*)&Ot[c * 68 + t4];
    }
}

extern "C" void kernel_launch(void* const* d_in, const int* in_sizes, int n_in,
                              void* d_out, int out_size, void* d_ws, size_t ws_size,
                              hipStream_t stream) {
    const float* qkv    = (const float*)d_in[0];
    const float* bboxes = (const float*)d_in[1];
    const float* nEmb   = (const float*)d_in[2];
    const float* pEmb   = (const float*)d_in[3];
    const float* W      = (const float*)d_in[4];
    short* wsS = (short*)d_ws;
    float* out = (float*)d_out;

    fuse_kernel<<<dim3(16, 24, 4), 256, 0, stream>>>(qkv, nEmb, pEmb, W, wsS);
    attn_fused<<<dim3(32, 16), 256, 0, stream>>>(wsS, bboxes, out);
}

// Round 12
// 143.218 us; speedup vs baseline: 1.0396x; 1.0396x over previous
//
#include <hip/hip_runtime.h>

// Problem constants (fixed by setup_inputs)
#define BS 4
#define NH 8
#define TT 1024         // T = 32*32
#define WROWS 1536      // 3*NH*CH
#define NOBJ 8
#define NT 65536        // per-bh tensor elems (64*1024)

// Workspace layout (short element offsets)
#define QNT_OFF  0
#define KNT_OFF  2097152
#define VNCS_OFF 4194304
#define QFT_OFF  6291456
#define KFT_OFF  8388608
#define VFT_OFF  10485760

typedef __attribute__((ext_vector_type(8))) short short8;
typedef __attribute__((ext_vector_type(4))) float v4f;

__device__ __forceinline__ short f2bf(float f) {
    unsigned u = __float_as_uint(f);
    u = (u + 0x7FFF + ((u >> 16) & 1)) >> 16;   // RNE
    return (short)u;
}
// packed f32x2 -> bf16x2 (RNE), lo = a, hi = b
__device__ __forceinline__ unsigned cvtpk(float a, float b) {
    unsigned u;
    asm("v_cvt_pk_bf16_f32 %0, %1, %2" : "=v"(u) : "v"(a), "v"(b));
    return u;
}
// 2^x via the HW transcendental (avoids glibc __exp2f name clash)
__device__ __forceinline__ float fexp2(float x) {
    float r;
    asm("v_exp_f32 %0, %1" : "=v"(r) : "v"(x));
    return r;
}
// NEW s-permutation pi'(s): for s = 32m+16a+4q+r -> p = 32m+8q+4a+r.
// Chosen so the swapped-QK^T in-register P layout (lane (ln,qd) holds
// S^T[s=16nn+4qd+r][q=ln]) is a VALID PV A-fragment with no cross-lane moves:
// lane's (nn,r) value sits at its own k-slot 8qd+4(nn&1)+r of MFMA m=nn>>1.
__device__ __forceinline__ int piP(int s) {
    return 32 * (s >> 5) + 8 * ((s >> 2) & 3) + 4 * ((s >> 4) & 1) + (s & 3);
}

__device__ __forceinline__ void get_region(const float* __restrict__ bb,
                                           int& i0, int& j0, int& hh, int& ww) {
    float x = bb[0], y = bb[1], bw = bb[2], bh = bb[3];
    float i0f = fminf(31.0f, floorf(y * 32.0f));
    float j0f = fminf(31.0f, floorf(x * 32.0f));
    float i1f = i0f + fmaxf(1.0f, ceilf(bh * 32.0f));
    float j1f = j0f + fmaxf(1.0f, ceilf(bw * 32.0f));
    i0 = (int)i0f; j0 = (int)j0f;
    int i1 = min(32, (int)i1f);
    int j1 = min(32, (int)j1f);
    hh = i1 - i0; ww = j1 - j0;
}

// ---------------------------------------------------------------------------
// Kernel 1: fused projection + layout conversion on MFMA (R7 structure).
// ONLY change vs R11: null V is pre-permuted with piP instead of the old pi.
// Outputs: q/k/fgV transposed [t][c]; null V [c][piP(p)] per 64-tile.
// Q scaled by 0.125*log2(e) so attention uses exp2.
// ---------------------------------------------------------------------------
__global__ __launch_bounds__(256)
void fuse_kernel(const float* __restrict__ qkv, const float* __restrict__ nEmb,
                 const float* __restrict__ pEmb, const float* __restrict__ W,
                 short* __restrict__ wsS) {
    __shared__ __align__(16) short Ent[64 * 72];
    __shared__ __align__(16) short Ept[64 * 72];
    __shared__ __align__(16) short sbuf[64 * 72];
    int t0 = blockIdx.x * 64;
    int r0 = blockIdx.y * 64;
    int b  = blockIdx.z;
    int tid = threadIdx.x;
    int w = tid >> 6, lane = tid & 63, ln = lane & 15, qd = lane >> 4;

    // stage E (null & prompt) transposed to bf16 [t][e], pitch 72
    {
        int e  = tid >> 4;
        int t4 = (tid & 15) * 4;
#pragma unroll
        for (int p = 0; p < 4; ++p) {
            int ee = p * 16 + e;
            float4 n4 = *(const float4*)&nEmb[(b * 64 + ee) * TT + t0 + t4];
            float4 p4 = *(const float4*)&pEmb[(b * 64 + ee) * TT + t0 + t4];
            Ent[(t4 + 0) * 72 + ee] = f2bf(n4.x); Ent[(t4 + 1) * 72 + ee] = f2bf(n4.y);
            Ent[(t4 + 2) * 72 + ee] = f2bf(n4.z); Ent[(t4 + 3) * 72 + ee] = f2bf(n4.w);
            Ept[(t4 + 0) * 72 + ee] = f2bf(p4.x); Ept[(t4 + 1) * 72 + ee] = f2bf(p4.y);
            Ept[(t4 + 2) * 72 + ee] = f2bf(p4.z); Ept[(t4 + 3) * 72 + ee] = f2bf(p4.w);
        }
    }
    // W A-fragments (bf16) direct from global: lane ln -> row r0+16w+ln
    short8 aw0, aw1;
    {
        const float* wp = &W[(r0 + 16 * w + ln) * 64 + qd * 8];
        float4 f0 = *(const float4*)wp;
        float4 f1 = *(const float4*)(wp + 4);
        float4 f2 = *(const float4*)(wp + 32);
        float4 f3 = *(const float4*)(wp + 36);
        uint4 u0, u1;
        u0.x = cvtpk(f0.x, f0.y); u0.y = cvtpk(f0.z, f0.w);
        u0.z = cvtpk(f1.x, f1.y); u0.w = cvtpk(f1.z, f1.w);
        u1.x = cvtpk(f2.x, f2.y); u1.y = cvtpk(f2.z, f2.w);
        u1.z = cvtpk(f3.x, f3.y); u1.w = cvtpk(f3.z, f3.w);
        aw0 = *(short8*)&u0; aw1 = *(short8*)&u1;
    }
    __syncthreads();
    // MFMA: D[row=16w+4qd+i][col=nn*16+ln] = sum_e W[row][e]*E[e][col]
    v4f accN[4], accP[4];
#pragma unroll
    for (int nn = 0; nn < 4; ++nn) {
        const short* bp = &Ent[(nn * 16 + ln) * 72 + qd * 8];
        short8 b0 = *(const short8*)bp;
        short8 b1 = *(const short8*)(bp + 32);
        v4f z = (v4f){0.f, 0.f, 0.f, 0.f};
        z = __builtin_amdgcn_mfma_f32_16x16x32_bf16(aw0, b0, z, 0, 0, 0);
        z = __builtin_amdgcn_mfma_f32_16x16x32_bf16(aw1, b1, z, 0, 0, 0);
        accN[nn] = z;
        const short* cp = &Ept[(nn * 16 + ln) * 72 + qd * 8];
        short8 c0 = *(const short8*)cp;
        short8 c1 = *(const short8*)(cp + 32);
        v4f y = (v4f){0.f, 0.f, 0.f, 0.f};
        y = __builtin_amdgcn_mfma_f32_16x16x32_bf16(aw0, c0, y, 0, 0, 0);
        y = __builtin_amdgcn_mfma_f32_16x16x32_bf16(aw1, c1, y, 0, 0, 0);
        accP[nn] = y;
    }
    // add qkv + scale
    int sec = (r0 % 192) / 64;          // 0=q 1=k 2=v
    int h = r0 / 192, bh = b * 8 + h;
    float sc = (sec == 0) ? 0.18033688f : 1.0f;   // 0.125*log2e folded into Q
    float xan[4][4], xap[4][4];                    // [nn][i]
#pragma unroll
    for (int nn = 0; nn < 4; ++nn)
#pragma unroll
        for (int i = 0; i < 4; ++i) {
            int r = r0 + 16 * w + 4 * qd + i;
            float x = qkv[(b * WROWS + r) * TT + t0 + nn * 16 + ln];
            xan[nn][i] = (accN[nn][i] + x) * sc;
            xap[nn][i] = (accP[nn][i] + x) * sc;
        }

    if (sec == 2) {
        // pass 1: null V pre-permuted [c][piP(p)]: value at local t-pos
        // p = 16nn+ln -> column 32*(nn>>1) + 4*(nn&1) + 8*(ln>>2) + (ln&3)
        short* Vn = wsS + VNCS_OFF + bh * NT;
        __syncthreads();
#pragma unroll
        for (int nn = 0; nn < 4; ++nn) {
            int colb = 32 * (nn >> 1) + 4 * (nn & 1) + 8 * (ln >> 2) + (ln & 3);
#pragma unroll
            for (int i = 0; i < 4; ++i)
                sbuf[(16 * w + 4 * qd + i) * 72 + colb] = f2bf(xan[nn][i]);
        }
        __syncthreads();
#pragma unroll
        for (int rep = 0; rep < 2; ++rep) {
            int idx = rep * 256 + tid; int cl = idx >> 3, c8 = idx & 7;
            *(short8*)&Vn[cl * TT + t0 + c8 * 8] = *(const short8*)&sbuf[cl * 72 + c8 * 8];
        }
        __syncthreads();
        // pass 2: fg V transposed [t][c]: row t = nn*16+ln, cols 16w+4qd..+3
        short* dst = wsS + VFT_OFF + bh * NT + t0 * 64;
#pragma unroll
        for (int nn = 0; nn < 4; ++nn) {
            uint2 u; u.x = cvtpk(xap[nn][0], xap[nn][1]); u.y = cvtpk(xap[nn][2], xap[nn][3]);
            *(uint2*)&sbuf[(nn * 16 + ln) * 72 + 16 * w + 4 * qd] = u;
        }
        __syncthreads();
#pragma unroll
        for (int rep = 0; rep < 2; ++rep) {
            int idx = rep * 256 + tid; int tl = idx >> 3, c8 = idx & 7;
            *(short8*)&dst[tl * 64 + c8 * 8] = *(const short8*)&sbuf[tl * 72 + c8 * 8];
        }
    } else {
        short* dn = wsS + (sec == 0 ? QNT_OFF : KNT_OFF) + bh * NT + t0 * 64;
        short* df = wsS + (sec == 0 ? QFT_OFF : KFT_OFF) + bh * NT + t0 * 64;
        __syncthreads();
        // pass 1: null, transposed [t][c]
#pragma unroll
        for (int nn = 0; nn < 4; ++nn) {
            uint2 u; u.x = cvtpk(xan[nn][0], xan[nn][1]); u.y = cvtpk(xan[nn][2], xan[nn][3]);
            *(uint2*)&sbuf[(nn * 16 + ln) * 72 + 16 * w + 4 * qd] = u;
        }
        __syncthreads();
#pragma unroll
        for (int rep = 0; rep < 2; ++rep) {
            int idx = rep * 256 + tid; int tl = idx >> 3, c8 = idx & 7;
            *(short8*)&dn[tl * 64 + c8 * 8] = *(const short8*)&sbuf[tl * 72 + c8 * 8];
        }
        __syncthreads();
        // pass 2: fg, transposed [t][c]
#pragma unroll
        for (int nn = 0; nn < 4; ++nn) {
            uint2 u; u.x = cvtpk(xap[nn][0], xap[nn][1]); u.y = cvtpk(xap[nn][2], xap[nn][3]);
            *(uint2*)&sbuf[(nn * 16 + ln) * 72 + 16 * w + 4 * qd] = u;
        }
        __syncthreads();
#pragma unroll
        for (int rep = 0; rep < 2; ++rep) {
            int idx = rep * 256 + tid; int tl = idx >> 3, c8 = idx & 7;
            *(short8*)&df[tl * 64 + c8 * 8] = *(const short8*)&sbuf[tl * 72 + c8 * 8];
        }
    }
}

// ---------------------------------------------------------------------------
// Kernel 2: fused null + foreground attention. Change vs R11 (single change):
// SWAPPED QK^T (S^T = mfma(K, Q)) keeps P fully IN REGISTERS — the P LDS
// round-trip (pack/write/lgkmwait/read, a hard intra-tile serialization)
// is deleted. V staged under piP so in-register P is directly a PV A-frag.
// Q loaded one-shot direct from global (no Q staging/barriers). Row-sum is
// now 1 scalar + 2 shfl_xor. Dbuf staging + bh-major grid kept from R10/R11.
// ---------------------------------------------------------------------------
__global__ __launch_bounds__(256)
void attn_fused(const short* __restrict__ wsS, const float* __restrict__ bboxes,
                float* __restrict__ out) {
    __shared__ __align__(16) short lds[18432];   // K[2] + V[2], 36 KB
    __shared__ unsigned short tmap[1024];
    short* Kb0 = lds;             // K buffers [64][72] x2
    short* Kb1 = lds + 4608;
    short* Vb0 = lds + 9216;      // V buffers [64][72] x2 ([c][piP(s)])
    short* Vb1 = lds + 13824;
    float* Ot  = (float*)lds;     // epilogue alias [64][68] floats = 17408 B
    int bh = blockIdx.x, rt = blockIdx.y;   // bh-major: XCD = bh % 8
    int b = bh >> 3, h = bh & 7;
    int t0 = rt * 64;
    int tid = threadIdx.x;
    int w = tid >> 6, lane = tid & 63, ln = lane & 15, qd = lane >> 4;
    const short* QnT = wsS + QNT_OFF + bh * NT;
    const short* KnT = wsS + KNT_OFF + bh * NT;
    const short* Vn  = wsS + VNCS_OFF + bh * NT;   // pre-permuted [c][piP]
    const short* QfT = wsS + QFT_OFF + bh * NT;
    const short* KfT = wsS + KFT_OFF + bh * NT;
    const short* VfT = wsS + VFT_OFF + bh * NT;
    int sidx = tid, scell = sidx >> 3, sc8 = sidx & 7;      // staging coords lo
    int sidx2 = 256 + tid, scell2 = sidx2 >> 3, sc82 = sidx2 & 7;

    // ================= Phase 1: null attention =================
    // Q one-shot direct from global (B-operand fragment)
    short8 aq0 = *(const short8*)&QnT[(t0 + 16 * w + ln) * 64 + qd * 8];
    short8 aq1 = *(const short8*)&QnT[(t0 + 16 * w + ln) * 64 + 32 + qd * 8];
    v4f O[4]; float l = 0.f;
#pragma unroll
    for (int cc = 0; cc < 4; ++cc) O[cc] = (v4f){0.f, 0.f, 0.f, 0.f};
    short8 kreg[2], vreg[2];
    // prologue: tile0 -> buf0; prefetch tile1 into regs
    kreg[0] = *(const short8*)&KnT[scell * 64 + sc8 * 8];
    kreg[1] = *(const short8*)&KnT[scell2 * 64 + sc82 * 8];
    vreg[0] = *(const short8*)&Vn[scell * TT + sc8 * 8];
    vreg[1] = *(const short8*)&Vn[scell2 * TT + sc82 * 8];
    *(short8*)&Kb0[scell * 72 + sc8 * 8]  = kreg[0];
    *(short8*)&Kb0[scell2 * 72 + sc82 * 8] = kreg[1];
    *(short8*)&Vb0[scell * 72 + sc8 * 8]  = vreg[0];
    *(short8*)&Vb0[scell2 * 72 + sc82 * 8] = vreg[1];
    kreg[0] = *(const short8*)&KnT[(64 + scell) * 64 + sc8 * 8];
    kreg[1] = *(const short8*)&KnT[(64 + scell2) * 64 + sc82 * 8];
    vreg[0] = *(const short8*)&Vn[scell * TT + 64 + sc8 * 8];
    vreg[1] = *(const short8*)&Vn[scell2 * TT + 64 + sc82 * 8];
    __syncthreads();   // buf0 ready
    for (int ct = 0; ct < 16; ++ct) {
        const short* Kc = (ct & 1) ? Kb1 : Kb0;
        const short* Vc = (ct & 1) ? Vb1 : Vb0;
        short* Kn_ = (ct & 1) ? Kb0 : Kb1;
        short* Vn_ = (ct & 1) ? Vb0 : Vb1;
        if (ct < 15) {
            *(short8*)&Kn_[scell * 72 + sc8 * 8]  = kreg[0];
            *(short8*)&Kn_[scell2 * 72 + sc82 * 8] = kreg[1];
            *(short8*)&Vn_[scell * 72 + sc8 * 8]  = vreg[0];
            *(short8*)&Vn_[scell2 * 72 + sc82 * 8] = vreg[1];
        }
        if (ct < 14) {
            int s0 = (ct + 2) * 64;
            kreg[0] = *(const short8*)&KnT[(s0 + scell) * 64 + sc8 * 8];
            kreg[1] = *(const short8*)&KnT[(s0 + scell2) * 64 + sc82 * 8];
            vreg[0] = *(const short8*)&Vn[scell * TT + s0 + sc8 * 8];
            vreg[1] = *(const short8*)&Vn[scell2 * TT + s0 + sc82 * 8];
        }
        // swapped QK^T: S^T[s=16nn+4qd+r][q=16w+ln]
        v4f S[4];
#pragma unroll
        for (int nn = 0; nn < 4; ++nn) {
            short8 k0 = *(const short8*)&Kc[(nn * 16 + ln) * 72 + qd * 8];
            short8 k1 = *(const short8*)&Kc[(nn * 16 + ln) * 72 + 32 + qd * 8];
            v4f z = (v4f){0.f, 0.f, 0.f, 0.f};
            z = __builtin_amdgcn_mfma_f32_16x16x32_bf16(k0, aq0, z, 0, 0, 0);
            z = __builtin_amdgcn_mfma_f32_16x16x32_bf16(k1, aq1, z, 0, 0, 0);
            S[nn] = z;
        }
        // exp in registers; P stays in registers (valid A-frag under piP)
        float p[4][4];
#pragma unroll
        for (int nn = 0; nn < 4; ++nn)
#pragma unroll
            for (int r = 0; r < 4; ++r) {
                p[nn][r] = fexp2(S[nn][r]);
                l += p[nn][r];
            }
        uint4 ua, ub;
        ua.x = cvtpk(p[0][0], p[0][1]); ua.y = cvtpk(p[0][2], p[0][3]);
        ua.z = cvtpk(p[1][0], p[1][1]); ua.w = cvtpk(p[1][2], p[1][3]);
        ub.x = cvtpk(p[2][0], p[2][1]); ub.y = cvtpk(p[2][2], p[2][3]);
        ub.z = cvtpk(p[3][0], p[3][1]); ub.w = cvtpk(p[3][2], p[3][3]);
        short8 ap0 = *(short8*)&ua, ap1 = *(short8*)&ub;
#pragma unroll
        for (int cc = 0; cc < 4; ++cc) {
            short8 bv0 = *(const short8*)&Vc[(cc * 16 + ln) * 72 + qd * 8];
            short8 bv1 = *(const short8*)&Vc[(cc * 16 + ln) * 72 + 32 + qd * 8];
            O[cc] = __builtin_amdgcn_mfma_f32_16x16x32_bf16(ap0, bv0, O[cc], 0, 0, 0);
            O[cc] = __builtin_amdgcn_mfma_f32_16x16x32_bf16(ap1, bv1, O[cc], 0, 0, 0);
        }
        __syncthreads();   // publish next buf; all reads of cur done
    }
    v4f Onull[4];
    {
        float rs = l;
        rs += __shfl_xor(rs, 16, 64);
        rs += __shfl_xor(rs, 32, 64);   // full row-sum for q-row 16w+ln
#pragma unroll
        for (int r = 0; r < 4; ++r) {
            float inv = 1.0f / __shfl(rs, 4 * qd + r, 64);  // row 4qd+r
#pragma unroll
            for (int cc = 0; cc < 4; ++cc) Onull[cc][r] = O[cc][r] * inv;
        }
    }

    // ================= Phase 2: foreground objects =================
    aq0 = *(const short8*)&QfT[(t0 + 16 * w + ln) * 64 + qd * 8];
    aq1 = *(const short8*)&QfT[(t0 + 16 * w + ln) * 64 + 32 + qd * 8];
    v4f Oacc[4]; float cnt[4];
#pragma unroll
    for (int r = 0; r < 4; ++r) cnt[r] = 0.f;
#pragma unroll
    for (int cc = 0; cc < 4; ++cc) Oacc[cc] = (v4f){0.f, 0.f, 0.f, 0.f};
    int pA = piP(scell), pB = piP(scell2);

    for (int o = 0; o < NOBJ; ++o) {
        int i0, j0, hh, ww;
        get_region(&bboxes[(b * NOBJ + o) * 5], i0, j0, hh, ww);
        int i1 = i0 + hh;
        if (i0 > 2 * rt + 1 || i1 <= 2 * rt) continue;   // uniform per block
        int R = hh * ww;
        for (int idx = tid; idx < R; idx += 256) {
            int ri = idx / ww; int rj = idx - ri * ww;
            tmap[idx] = (unsigned short)((i0 + ri) * 32 + j0 + rj);
        }
        __syncthreads();   // tmap visible; prior buffer reads all fenced
        l = 0.f;
#pragma unroll
        for (int cc = 0; cc < 4; ++cc) O[cc] = (v4f){0.f, 0.f, 0.f, 0.f};
        int nct = (R + 63) >> 6;
        // prologue: tile0 -> buf0; prefetch tile1 into regs
        {
            int tA = tmap[min(scell, R - 1)];
            int tB = tmap[min(scell2, R - 1)];
            kreg[0] = *(const short8*)&KfT[tA * 64 + sc8 * 8];
            kreg[1] = *(const short8*)&KfT[tB * 64 + sc82 * 8];
            vreg[0] = *(const short8*)&VfT[tA * 64 + sc8 * 8];
            vreg[1] = *(const short8*)&VfT[tB * 64 + sc82 * 8];
        }
        *(short8*)&Kb0[scell * 72 + sc8 * 8]  = kreg[0];
        *(short8*)&Kb0[scell2 * 72 + sc82 * 8] = kreg[1];
#pragma unroll
        for (int jj = 0; jj < 8; ++jj) {
            int j = (jj + sc8) & 7;
            Vb0[(sc8 * 8 + j) * 72 + pA] = vreg[0][j];
        }
#pragma unroll
        for (int jj = 0; jj < 8; ++jj) {
            int j = (jj + sc82) & 7;
            Vb0[(sc82 * 8 + j) * 72 + pB] = vreg[1][j];
        }
        if (nct > 1) {
            int tA = tmap[min(64 + scell, R - 1)];
            int tB = tmap[min(64 + scell2, R - 1)];
            kreg[0] = *(const short8*)&KfT[tA * 64 + sc8 * 8];
            kreg[1] = *(const short8*)&KfT[tB * 64 + sc82 * 8];
            vreg[0] = *(const short8*)&VfT[tA * 64 + sc8 * 8];
            vreg[1] = *(const short8*)&VfT[tB * 64 + sc82 * 8];
        }
        __syncthreads();   // buf0 ready
        for (int ct = 0; ct < nct; ++ct) {
            int sb = ct * 64;
            const short* Kc = (ct & 1) ? Kb1 : Kb0;
            const short* Vc = (ct & 1) ? Vb1 : Vb0;
            short* Kn_ = (ct & 1) ? Kb0 : Kb1;
            short* Vn_ = (ct & 1) ? Vb0 : Vb1;
            if (ct + 1 < nct) {
                *(short8*)&Kn_[scell * 72 + sc8 * 8]  = kreg[0];
                *(short8*)&Kn_[scell2 * 72 + sc82 * 8] = kreg[1];
#pragma unroll
                for (int jj = 0; jj < 8; ++jj) {
                    int j = (jj + sc8) & 7;
                    Vn_[(sc8 * 8 + j) * 72 + pA] = vreg[0][j];
                }
#pragma unroll
                for (int jj = 0; jj < 8; ++jj) {
                    int j = (jj + sc82) & 7;
                    Vn_[(sc82 * 8 + j) * 72 + pB] = vreg[1][j];
                }
            }
            if (ct + 2 < nct) {
                int s0 = sb + 128;
                int tA = tmap[min(s0 + scell, R - 1)];
                int tB = tmap[min(s0 + scell2, R - 1)];
                kreg[0] = *(const short8*)&KfT[tA * 64 + sc8 * 8];
                kreg[1] = *(const short8*)&KfT[tB * 64 + sc82 * 8];
                vreg[0] = *(const short8*)&VfT[tA * 64 + sc8 * 8];
                vreg[1] = *(const short8*)&VfT[tB * 64 + sc82 * 8];
            }
            // swapped QK^T
            v4f S[4];
#pragma unroll
            for (int nn = 0; nn < 4; ++nn) {
                short8 k0 = *(const short8*)&Kc[(nn * 16 + ln) * 72 + qd * 8];
                short8 k1 = *(const short8*)&Kc[(nn * 16 + ln) * 72 + 32 + qd * 8];
                v4f z = (v4f){0.f, 0.f, 0.f, 0.f};
                z = __builtin_amdgcn_mfma_f32_16x16x32_bf16(k0, aq0, z, 0, 0, 0);
                z = __builtin_amdgcn_mfma_f32_16x16x32_bf16(k1, aq1, z, 0, 0, 0);
                S[nn] = z;
            }
            // exp + mask: this lane's s = sb + 16nn + 4qd + r
            float p[4][4];
            int sbase = sb + 4 * qd;
#pragma unroll
            for (int nn = 0; nn < 4; ++nn)
#pragma unroll
                for (int r = 0; r < 4; ++r) {
                    float vm = (sbase + 16 * nn + r) < R ? 1.f : 0.f;
                    p[nn][r] = fexp2(S[nn][r]) * vm;
                    l += p[nn][r];
                }
            uint4 ua, ub;
            ua.x = cvtpk(p[0][0], p[0][1]); ua.y = cvtpk(p[0][2], p[0][3]);
            ua.z = cvtpk(p[1][0], p[1][1]); ua.w = cvtpk(p[1][2], p[1][3]);
            ub.x = cvtpk(p[2][0], p[2][1]); ub.y = cvtpk(p[2][2], p[2][3]);
            ub.z = cvtpk(p[3][0], p[3][1]); ub.w = cvtpk(p[3][2], p[3][3]);
            short8 ap0 = *(short8*)&ua, ap1 = *(short8*)&ub;
#pragma unroll
            for (int cc = 0; cc < 4; ++cc) {
                short8 bv0 = *(const short8*)&Vc[(cc * 16 + ln) * 72 + qd * 8];
                short8 bv1 = *(const short8*)&Vc[(cc * 16 + ln) * 72 + 32 + qd * 8];
                O[cc] = __builtin_amdgcn_mfma_f32_16x16x32_bf16(ap0, bv0, O[cc], 0, 0, 0);
                O[cc] = __builtin_amdgcn_mfma_f32_16x16x32_bf16(ap1, bv1, O[cc], 0, 0, 0);
            }
            __syncthreads();   // publish next buf; all reads of cur done
        }
        // finalize object: accumulate rows inside region
        {
            float rs = l;
            rs += __shfl_xor(rs, 16, 64);
            rs += __shfl_xor(rs, 32, 64);
#pragma unroll
            for (int r = 0; r < 4; ++r) {
                float inv = 1.0f / __shfl(rs, 4 * qd + r, 64);
                int t = t0 + 16 * w + 4 * qd + r;
                int ti = t >> 5, tj = t & 31;
                bool in = (ti >= i0) && (ti < i1) && (tj >= j0) && (tj < j0 + ww);
                if (in) {
                    cnt[r] += 1.f;
#pragma unroll
                    for (int cc = 0; cc < 4; ++cc) Oacc[cc][r] += O[cc][r] * inv;
                }
            }
        }
    }

    // ================= Epilogue =================
    __syncthreads();
#pragma unroll
    for (int r = 0; r < 4; ++r) {
        int tl = 16 * w + 4 * qd + r;
        float icnt = cnt[r] > 0.f ? 1.0f / cnt[r] : 0.f;
#pragma unroll
        for (int cc = 0; cc < 4; ++cc) {
            float val = cnt[r] > 0.f ? Oacc[cc][r] * icnt : Onull[cc][r];
            Ot[(cc * 16 + ln) * 68 + tl] = val;
        }
    }
    __syncthreads();
    int obase = (b * 512 + h * 64) * TT + t0;
#pragma unroll
    for (int rep = 0; rep < 4; ++rep) {
        int idx = rep * 256 + tid; int c = idx >> 4, t4 = (idx & 15) * 4;
        *(float4*)&out[obase + c * TT + t4] = *(float4*)&Ot[c * 68 + t4];
    }
}

extern "C" void kernel_launch(void* const* d_in, const int* in_sizes, int n_in,
                              void* d_out, int out_size, void* d_ws, size_t ws_size,
                              hipStream_t stream) {
    const float* qkv    = (const float*)d_in[0];
    const float* bboxes = (const float*)d_in[1];
    const float* nEmb   = (const float*)d_in[2];
    const float* pEmb   = (const float*)d_in[3];
    const float* W      = (const float*)d_in[4];
    short* wsS = (short*)d_ws;
    float* out = (float*)d_out;

    fuse_kernel<<<dim3(16, 24, 4), 256, 0, stream>>>(qkv, nEmb, pEmb, W, wsS);
    attn_fused<<<dim3(32, 16), 256, 0, stream>>>(wsS, bboxes, out);
}